// Round 6
// baseline (938.295 us; speedup 1.0000x reference)
//
#include <hip/hip_runtime.h>
#include <hip/hip_bf16.h>

// ---------------------------------------------------------------------------
// C4 equivariant CNN, round 6.
//  - conv1..5: MFMA implicit-GEMM, split-bf16 (hi/lo) 3-term products.
//    NEW: each wave owns one x-tile and ALL oc-tiles (A ds_reads /3),
//    RPW=2 output rows/wave where even, single launch + XCD swizzle.
//  - conv0: 24 oc x 4 x per thread, writes full 64B NHWC lines (coalesced).
//  - memsets replaced by halo/ch-pad prep kernels.
// ---------------------------------------------------------------------------

typedef short s16x8 __attribute__((ext_vector_type(8)));
typedef __bf16 bf16x8 __attribute__((ext_vector_type(8)));
typedef float f32x4 __attribute__((ext_vector_type(4)));
typedef unsigned short u16;

__device__ __forceinline__ u16 f2bf(float f) {      // RNE fp32 -> bf16 bits
    unsigned u = __float_as_uint(f);
    return (u16)((u + 0x7FFFu + ((u >> 16) & 1u)) >> 16);
}
__device__ __forceinline__ float bf2f(u16 h) {
    return __uint_as_float(((unsigned)h) << 16);
}

__device__ __forceinline__ void rot_src(int r, int K, int y, int x, int& sy, int& sx) {
    switch (r & 3) {
        case 0: sy = y;         sx = x;         break;
        case 1: sy = x;         sx = K - 1 - y; break;
        case 2: sy = K - 1 - y; sx = K - 1 - x; break;
        default: sy = K - 1 - x; sx = y;        break;
    }
}

// w0: (6,1,7,7) -> F0T: [49][24] fp32
__global__ void lift_w0T_kernel(const float* __restrict__ w, float* __restrict__ f) {
    const int K = 7, KK = 49, OC = 24;
    int idx = blockIdx.x * blockDim.x + threadIdx.x;
    if (idx >= KK * OC) return;
    int oc = idx % OC; int kk = idx / OC;
    int y = kk / K, x = kk % K;
    int r = oc & 3, o = oc >> 2;
    int sy, sx; rot_src(r, K, y, x, sy, sx);
    f[idx] = w[o * KK + sy * K + sx];
}

// group-transform + split + pack into MFMA B-fragment order.
// elem idx = (((kpos*KC + kc)*NT + nc)*64 + lane)*8 + j
//   k = kc*32 + (lane>>4)*8 + j ; oc = nc*16 + (lane&15); hi at idx, lo at idx+total
__global__ void wfrag_kernel(const float* __restrict__ w, u16* __restrict__ wf,
                             int O, int I, int KC, int NT, int total) {
    int idx = blockIdx.x * blockDim.x + threadIdx.x;
    if (idx >= total) return;
    int j = idx & 7;
    int lane = (idx >> 3) & 63;
    int rest = idx >> 9;
    int nc = rest % NT; rest /= NT;
    int kc = rest % KC; int kpos = rest / KC;
    int ky = kpos / 5, kx = kpos % 5;
    int kk = ((lane >> 4) << 3) + j;
    int ic = kc * 32 + kk;
    int oc = nc * 16 + (lane & 15);
    float val = 0.f;
    if (ic < I * 4) {
        int o = oc >> 2, r = oc & 3, i = ic >> 2, s = ic & 3;
        int g = (s - r + 4) & 3;
        int sy, sx; rot_src(r, 5, ky, kx, sy, sx);
        val = w[(((o * I + i) * 4 + g) * 25) + sy * 5 + sx];
    }
    u16 hb = f2bf(val);
    u16 lb = f2bf(val - bf2f(hb));
    wf[idx] = hb;
    wf[idx + total] = lb;
}

// x (64,1,96,96) -> xp (64, 98, 100) fp32 with 1-border (pre-zeroed)
__global__ void pad_x_kernel(const float* __restrict__ x, float* __restrict__ xp) {
    int idx = blockIdx.x * blockDim.x + threadIdx.x;
    if (idx >= 64 * 96 * 96) return;
    int c = idx % 96; int t = idx / 96;
    int r = t % 96; int n = t / 96;
    xp[((size_t)n * 98 + r + 1) * 100 + c + 1] = x[idx];
}

// zero halo (thickness 2) fully + channel-pad chunks [CR8, ICO/8) elsewhere,
// both hi and lo planes. NHW = N*Hp*Wp.
__global__ void prep_pad_kernel(u16* __restrict__ buf, long LO, int NHW,
                                int Hp, int Wp, int ICO, int CR8) {
    int idx = blockIdx.x * blockDim.x + threadIdx.x;
    if (idx >= NHW) return;
    int c = idx % Wp; int t = idx / Wp;
    int r = t % Hp; int n = t / Hp;
    bool halo = (r < 2) || (r >= Hp - 2) || (c < 2) || (c >= Wp - 2);
    int c0 = halo ? 0 : CR8, c1 = ICO >> 3;
    if (c0 >= c1) return;
    size_t base = (((size_t)n * Hp + r) * Wp + c) * ICO;
    s16x8 z = {0, 0, 0, 0, 0, 0, 0, 0};
    for (int cc = c0; cc < c1; ++cc) {
        *(s16x8*)(buf + base + cc * 8) = z;
        *(s16x8*)(buf + LO + base + cc * 8) = z;
    }
}

// conv0: fp32 direct (IC=1, K=7, pad=1). One thread: ALL 24 oc x 4 x.
// Writes full 64B NHWC lines (ch 0..23 data, 24..31 zero), hi and lo planes.
__global__ __launch_bounds__(256) void conv0_kernel(
        const float* __restrict__ xp, const float* __restrict__ f0t,
        const float* __restrict__ b0, u16* __restrict__ p1, long p1LO) {
    int idx = blockIdx.x * blockDim.x + threadIdx.x;
    if (idx >= 64 * 92 * 23) return;
    int xq = idx % 23; int t = idx / 23;
    int oy = t % 92; int n = t / 92;
    float acc[24][4];
#pragma unroll
    for (int a = 0; a < 24; ++a)
#pragma unroll
        for (int b = 0; b < 4; ++b) acc[a][b] = 0.f;

    const float* ip = xp + ((size_t)n * 98 + oy) * 100 + xq * 4;
#pragma unroll
    for (int ky = 0; ky < 7; ++ky) {
        const float* row = ip + (size_t)ky * 100;
        float xv[12];
#pragma unroll
        for (int v = 0; v < 3; ++v)
            *reinterpret_cast<float4*>(&xv[4 * v]) =
                *reinterpret_cast<const float4*>(row + 4 * v);
#pragma unroll
        for (int kx = 0; kx < 7; ++kx) {
            const float* wp = f0t + (ky * 7 + kx) * 24;
#pragma unroll
            for (int qd = 0; qd < 6; ++qd) {
                float4 wv = *reinterpret_cast<const float4*>(wp + qd * 4);
#pragma unroll
                for (int jx = 0; jx < 4; ++jx) {
                    acc[qd * 4 + 0][jx] = fmaf(wv.x, xv[kx + jx], acc[qd * 4 + 0][jx]);
                    acc[qd * 4 + 1][jx] = fmaf(wv.y, xv[kx + jx], acc[qd * 4 + 1][jx]);
                    acc[qd * 4 + 2][jx] = fmaf(wv.z, xv[kx + jx], acc[qd * 4 + 2][jx]);
                    acc[qd * 4 + 3][jx] = fmaf(wv.w, xv[kx + jx], acc[qd * 4 + 3][jx]);
                }
            }
        }
    }
    float bv[6];
#pragma unroll
    for (int qd = 0; qd < 6; ++qd) bv[qd] = b0[qd];

    size_t ob = (((size_t)n * 96 + oy + 2) * 96 + xq * 4 + 2) * 32;
#pragma unroll
    for (int jx = 0; jx < 4; ++jx) {
        s16x8 hv[4], lv[4];
#pragma unroll
        for (int cc = 0; cc < 3; ++cc)
#pragma unroll
            for (int e = 0; e < 8; ++e) {
                int ch = cc * 8 + e;
                float v = fmaxf(acc[ch][jx] + bv[ch >> 2], 0.f);
                u16 hb = f2bf(v);
                u16 lb = f2bf(v - bf2f(hb));
                hv[cc][e] = (short)hb; lv[cc][e] = (short)lb;
            }
        hv[3] = s16x8{0,0,0,0,0,0,0,0}; lv[3] = s16x8{0,0,0,0,0,0,0,0};
#pragma unroll
        for (int cc = 0; cc < 4; ++cc) {
            *(s16x8*)(p1 + ob + jx * 32 + cc * 8) = hv[cc];
            *(s16x8*)(p1 + p1LO + ob + jx * 32 + cc * 8) = lv[cc];
        }
    }
}

// ---------------------------------------------------------------------------
// MFMA conv. Waves split M (x-tiles, 16 conv-x each); each wave computes ALL
// NT oc-tiles and CR conv rows (POOL: 2 rows -> 1 pooled row; else RPW rows).
// ---------------------------------------------------------------------------
template <int IC32, int NT, int NW, int WT, bool POOL, int RPW, int XOFF>
__global__ __launch_bounds__(NW * 64) void conv_mfma_kernel(
        const u16* __restrict__ act, long actLO,
        const u16* __restrict__ wf, int wfLO,
        const float* __restrict__ bias,
        u16* __restrict__ outP, long outLO,
        float* __restrict__ outF,
        int Hp, int Wp, int OHB, int OH, int OW,
        int HpO, int WpO, int IC32O, int OWO) {
    constexpr int KC = IC32 / 32;
    constexpr int KC4 = IC32 / 8;            // 16B chunks per x per plane
    constexpr int CR = POOL ? 2 : RPW;       // conv rows per wave
    constexpr int R = 4 + CR;                // staged rows
    constexpr int RW = R * WT;
    constexpr int CST = RW + ((2 - (RW % 8) + 8) % 8);  // chunk stride ≡2 mod 8
    __shared__ u16 lds[2 * KC4 * CST * 8];

    // bijective XCD swizzle (gridDim.x % 8 == 0): same-n blocks share an XCD
    int q8 = gridDim.x >> 3;
    int wid = (blockIdx.x & 7) * q8 + (blockIdx.x >> 3);
    int oyb = wid % OHB;
    int n = wid / OHB;
    int rbase = (POOL ? 2 * oyb : RPW * oyb) + XOFF;

    const int CH = 2 * KC4;
    for (int u = threadIdx.x; u < RW * CH; u += NW * 64) {
        int c = u % CH; int rx = u / CH;
        int x = rx % WT, row = rx / WT;
        int sp = c / KC4, cc = c % KC4;
        s16x8 v = {0, 0, 0, 0, 0, 0, 0, 0};
        if (x < Wp && rbase + row < Hp)
            v = *(const s16x8*)(act + (size_t)sp * actLO +
                  (((size_t)n * Hp + rbase + row) * Wp + x) * IC32 + cc * 8);
        *(s16x8*)&lds[((sp * KC4 + cc) * CST + row * WT + x) * 8] = v;
    }
    __syncthreads();

    int wv = threadIdx.x >> 6;
    int lane = threadIdx.x & 63;
    int l15 = lane & 15, lg = lane >> 4;
    int rd0 = wv * 16 + XOFF + l15;

    f32x4 accP[CR][NT], accQ[CR][NT];
#pragma unroll
    for (int rw = 0; rw < CR; ++rw)
#pragma unroll
        for (int ncw = 0; ncw < NT; ++ncw) {
            accP[rw][ncw] = f32x4{0.f, 0.f, 0.f, 0.f};
            accQ[rw][ncw] = f32x4{0.f, 0.f, 0.f, 0.f};
        }

    const u16* wfw = wf + (size_t)lane * 8;

    for (int kpos = 0; kpos < 25; ++kpos) {
        int ky = kpos / 5, kx = kpos % 5;
#pragma unroll
        for (int kc = 0; kc < KC; ++kc) {
            int cc = kc * 4 + lg;
            bf16x8 af[CR][2];
            const u16* lA = &lds[(cc * CST + ky * WT + rd0 + kx) * 8];
#pragma unroll
            for (int rw = 0; rw < CR; ++rw) {
                af[rw][0] = *(const bf16x8*)(lA + rw * WT * 8);
                af[rw][1] = *(const bf16x8*)(lA + (KC4 * CST + rw * WT) * 8);
            }
#pragma unroll
            for (int ncw = 0; ncw < NT; ++ncw) {
                const u16* bp = wfw + ((size_t)(kpos * KC + kc) * NT + ncw) * 512;
                bf16x8 bh = *(const bf16x8*)bp;
                bf16x8 bl = *(const bf16x8*)(bp + wfLO);
#pragma unroll
                for (int rw = 0; rw < CR; ++rw) {
                    accP[rw][ncw] = __builtin_amdgcn_mfma_f32_16x16x32_bf16(
                        af[rw][0], bh, accP[rw][ncw], 0, 0, 0);
                    accQ[rw][ncw] = __builtin_amdgcn_mfma_f32_16x16x32_bf16(
                        af[rw][0], bl, accQ[rw][ncw], 0, 0, 0);
                    accQ[rw][ncw] = __builtin_amdgcn_mfma_f32_16x16x32_bf16(
                        af[rw][1], bh, accQ[rw][ncw], 0, 0, 0);
                }
            }
        }
    }

    // epilogue: C layout col(lane&15)=oc-within-tile, row((lane>>4)*4+j)=x
    int gx0 = wv * 16;
#pragma unroll
    for (int ncw = 0; ncw < NT; ++ncw) {
        int oc = ncw * 16 + l15;
        float bv = bias[oc >> 2];
        if constexpr (POOL) {
            float c0[4], c1[4];
#pragma unroll
            for (int j = 0; j < 4; ++j) {
                c0[j] = accP[0][ncw][j] + accQ[0][ncw][j];
                c1[j] = accP[1][ncw][j] + accQ[1][ncw][j];
            }
#pragma unroll
            for (int a2 = 0; a2 < 2; ++a2) {
                float mx = fmaxf(fmaxf(c0[2 * a2], c0[2 * a2 + 1]),
                                 fmaxf(c1[2 * a2], c1[2 * a2 + 1]));
                int xo = (gx0 + lg * 4 + 2 * a2) >> 1;
                if (xo < OWO) {
                    float v = fmaxf(mx + bv, 0.f);
                    u16 hb = f2bf(v);
                    u16 lb = f2bf(v - bf2f(hb));
                    size_t o = (((size_t)n * HpO + oyb + 2) * WpO + xo + 2) * IC32O + oc;
                    outP[o] = hb; outP[o + outLO] = lb;
                }
            }
        } else {
#pragma unroll
            for (int rw = 0; rw < CR; ++rw) {
                int oy = oyb * RPW + rw;
                if (oy < OH) {
#pragma unroll
                    for (int j = 0; j < 4; ++j) {
                        int gx = gx0 + lg * 4 + j;
                        if (gx < OW) {
                            float v = fmaxf(accP[rw][ncw][j] + accQ[rw][ncw][j] + bv, 0.f);
                            if (outF) {
                                outF[(((size_t)n * OH + oy) * OW + gx) * (NT * 16) + oc] = v;
                            } else {
                                u16 hb = f2bf(v);
                                u16 lb = f2bf(v - bf2f(hb));
                                size_t o = (((size_t)n * HpO + oy + 2) * WpO + gx + 2) * IC32O + oc;
                                outP[o] = hb; outP[o + outLO] = lb;
                            }
                        }
                    }
                }
            }
        }
    }
}

// mean over 21x21 spatial of NHWC fp32 [64][21][21][64] -> (64,64)
__global__ void mean_nhwc_kernel(const float* __restrict__ in, float* __restrict__ out) {
    __shared__ float sm[256];
    int n = blockIdx.x;
    int c = threadIdx.x & 63, q = threadIdx.x >> 6;
    float s = 0.f;
    for (int p = q; p < 441; p += 4) s += in[((size_t)n * 441 + p) * 64 + c];
    sm[threadIdx.x] = s;
    __syncthreads();
    if (q == 0) out[n * 64 + c] = (sm[c] + sm[c + 64] + sm[c + 128] + sm[c + 192]) * (1.0f / 441.0f);
}

// single block: fc1 (64x64, relu) then fc2 (10x64)
__global__ void fc_kernel(const float* __restrict__ mean, const float* __restrict__ fw1,
                          const float* __restrict__ fb1, const float* __restrict__ fw2,
                          const float* __restrict__ fb2, float* __restrict__ out) {
    __shared__ float m[4096];
    __shared__ float h1[4096];
    int tid = threadIdx.x;
    for (int i = tid; i < 4096; i += 256) m[i] = mean[i];
    __syncthreads();
    for (int i = tid; i < 4096; i += 256) {
        int n = i >> 6, j = i & 63;
        float s = fb1[j];
        for (int k = 0; k < 64; ++k) s = fmaf(m[n * 64 + k], fw1[j * 64 + k], s);
        h1[i] = fmaxf(s, 0.f);
    }
    __syncthreads();
    for (int i = tid; i < 640; i += 256) {
        int n = i / 10, j2 = i % 10;
        float s = fb2[j2];
        for (int j = 0; j < 64; ++j) s = fmaf(h1[n * 64 + j], fw2[j2 * 64 + j], s);
        out[i] = s;
    }
}

extern "C" void kernel_launch(void* const* d_in, const int* in_sizes, int n_in,
                              void* d_out, int out_size, void* d_ws, size_t ws_size,
                              hipStream_t stream) {
    const float* x   = (const float*)d_in[0];
    const float* w0  = (const float*)d_in[1];
    const float* b0  = (const float*)d_in[2];
    const float* w1  = (const float*)d_in[3];
    const float* b1  = (const float*)d_in[4];
    const float* w2  = (const float*)d_in[5];
    const float* b2  = (const float*)d_in[6];
    const float* w3  = (const float*)d_in[7];
    const float* b3  = (const float*)d_in[8];
    const float* w4  = (const float*)d_in[9];
    const float* b4  = (const float*)d_in[10];
    const float* w5  = (const float*)d_in[11];
    const float* b5  = (const float*)d_in[12];
    const float* fw1 = (const float*)d_in[13];
    const float* fb1 = (const float*)d_in[14];
    const float* fw2 = (const float*)d_in[15];
    const float* fb2 = (const float*)d_in[16];

    char* ws = (char*)d_ws;
    if (ws_size < 128827392ull) return;

    float* F0   = (float*)(ws + 0);
    u16*   WF1  = (u16*)(ws + 8192);
    u16*   WF2  = (u16*)(ws + 161792);
    u16*   WF3  = (u16*)(ws + 468992);
    u16*   WF4  = (u16*)(ws + 1083392);
    u16*   WF5  = (u16*)(ws + 2004992);
    float* MEANB= (float*)(ws + 2619392);
    float* XP   = (float*)(ws + 2635776);
    float* C5   = (float*)(ws + 5144576);
    u16*   A    = (u16*)(ws + 12369920);    // P1 / P3 / P5
    u16*   B    = (u16*)(ws + 87867392);    // P2 / P4
    const long P1LO = 18874368;   // 64*96*96*32
    const long P2LO = 10240000;   // 64*50*50*64
    const long P4LO = 4478976;    // 64*27*27*96

    // --- weight transforms ---
    hipLaunchKernelGGL(lift_w0T_kernel, dim3(5), dim3(256), 0, stream, w0, F0);
    hipLaunchKernelGGL(wfrag_kernel, dim3(150), dim3(256), 0, stream, w1, WF1, 12, 6, 1, 3, 38400);
    hipLaunchKernelGGL(wfrag_kernel, dim3(300), dim3(256), 0, stream, w2, WF2, 12, 12, 2, 3, 76800);
    hipLaunchKernelGGL(wfrag_kernel, dim3(600), dim3(256), 0, stream, w3, WF3, 24, 12, 2, 6, 153600);
    hipLaunchKernelGGL(wfrag_kernel, dim3(900), dim3(256), 0, stream, w4, WF4, 24, 24, 3, 6, 230400);
    hipLaunchKernelGGL(wfrag_kernel, dim3(600), dim3(256), 0, stream, w5, WF5, 16, 24, 3, 4, 153600);

    // --- input pad (fp32) ---
    hipMemsetAsync(XP, 0, 2508800, stream);
    hipLaunchKernelGGL(pad_x_kernel, dim3(2304), dim3(256), 0, stream, x, XP);

    // --- P1 halo prep + conv0 (conv0 writes full lines incl. ch-pad) ---
    hipLaunchKernelGGL(prep_pad_kernel, dim3((64*96*96 + 255)/256), dim3(256), 0, stream,
                       A, P1LO, 64*96*96, 96, 96, 32, 4);
    hipLaunchKernelGGL(conv0_kernel, dim3((64*92*23 + 255)/256), dim3(256), 0, stream,
                       XP, F0, b0, A, P1LO);

    // --- P2 prep + conv1 (+pool): P1 -> P2 [50][50][64] ---
    hipLaunchKernelGGL(prep_pad_kernel, dim3((64*50*50 + 255)/256), dim3(256), 0, stream,
                       B, P2LO, 64*50*50, 50, 50, 64, 6);
    hipLaunchKernelGGL((conv_mfma_kernel<32, 3, 6, 100, true, 1, 0>), dim3(64*46), dim3(384), 0, stream,
                       A, P1LO, WF1, 38400, b1, B, P2LO, (float*)nullptr,
                       96, 96, 46, 46, 92, 50, 50, 64, 46);

    // --- P3 prep + conv2: P2 -> P3 [50][50][64], RPW=2 ---
    hipLaunchKernelGGL(prep_pad_kernel, dim3((64*50*50 + 255)/256), dim3(256), 0, stream,
                       A, P2LO, 64*50*50, 50, 50, 64, 6);
    hipLaunchKernelGGL((conv_mfma_kernel<64, 3, 3, 52, false, 2, 0>), dim3(64*23), dim3(192), 0, stream,
                       B, P2LO, WF2, 76800, b2, A, P2LO, (float*)nullptr,
                       50, 50, 23, 46, 46, 50, 50, 64, 46);

    // --- P4 prep + conv3 (+pool): P3 -> P4 [27][27][96] ---
    hipLaunchKernelGGL(prep_pad_kernel, dim3((64*27*27 + 255)/256), dim3(256), 0, stream,
                       B, P4LO, 64*27*27, 27, 27, 96, 12);
    hipLaunchKernelGGL((conv_mfma_kernel<64, 6, 3, 52, true, 1, 0>), dim3(64*23), dim3(192), 0, stream,
                       A, P2LO, WF3, 153600, b3, B, P4LO, (float*)nullptr,
                       50, 50, 23, 23, 46, 27, 27, 96, 23);

    // --- P5 prep + conv4: P4 -> P5 [27][27][96] ---
    hipLaunchKernelGGL(prep_pad_kernel, dim3((64*27*27 + 255)/256), dim3(256), 0, stream,
                       A, P4LO, 64*27*27, 27, 27, 96, 12);
    hipLaunchKernelGGL((conv_mfma_kernel<96, 6, 2, 36, false, 1, 0>), dim3(64*23), dim3(128), 0, stream,
                       B, P4LO, WF4, 230400, b4, A, P4LO, (float*)nullptr,
                       27, 27, 23, 23, 23, 27, 27, 96, 23);

    // --- conv5: P5 -> C5 fp32 NHWC compact [21][21][64] ---
    hipLaunchKernelGGL((conv_mfma_kernel<96, 4, 2, 37, false, 1, 1>), dim3(64*21), dim3(128), 0, stream,
                       A, P4LO, WF5, 153600, b5, (u16*)A, 0, C5,
                       27, 27, 21, 21, 21, 27, 27, 96, 21);

    // --- mean + fc ---
    hipLaunchKernelGGL(mean_nhwc_kernel, dim3(64), dim3(256), 0, stream, C5, MEANB);
    hipLaunchKernelGGL(fc_kernel, dim3(1), dim3(256), 0, stream,
                       MEANB, fw1, fb1, fw2, fb2, (float*)d_out);
}

// Round 7
// 677.449 us; speedup vs baseline: 1.3850x; 1.3850x over previous
//
#include <hip/hip_runtime.h>
#include <hip/hip_bf16.h>

// ---------------------------------------------------------------------------
// C4 equivariant CNN, round 7: MFMA implicit-GEMM, split-bf16 (hi/lo).
// Fixes vs r6 (B-traffic explosion, occupancy collapse, bank conflicts):
//  - wave = MT x-tiles x NTW oc-tiles x CR rows (M/wave 48-96): B-frags are
//    loaded once per wave and reused across all M -> L2 B-traffic /4
//  - channel-split staging: stage 32ch (hi+lo = 8 chunks/x) per pass, acc
//    carried in registers across KC passes -> LDS 37-80 KB, 2-4 blocks/CU
//  - LDS [row][x][chunk] with chunk XOR-swizzle (c ^ (x&7)): staging writes
//    linear (conflict-free), compute reads spread 8 bank groups (2-way=free)
//  - all conv blocks 256 threads
// ---------------------------------------------------------------------------

typedef short s16x8 __attribute__((ext_vector_type(8)));
typedef __bf16 bf16x8 __attribute__((ext_vector_type(8)));
typedef float f32x4 __attribute__((ext_vector_type(4)));
typedef unsigned short u16;

__device__ __forceinline__ u16 f2bf(float f) {      // RNE fp32 -> bf16 bits
    unsigned u = __float_as_uint(f);
    return (u16)((u + 0x7FFFu + ((u >> 16) & 1u)) >> 16);
}
__device__ __forceinline__ float bf2f(u16 h) {
    return __uint_as_float(((unsigned)h) << 16);
}

__device__ __forceinline__ void rot_src(int r, int K, int y, int x, int& sy, int& sx) {
    switch (r & 3) {
        case 0: sy = y;         sx = x;         break;
        case 1: sy = x;         sx = K - 1 - y; break;
        case 2: sy = K - 1 - y; sx = K - 1 - x; break;
        default: sy = K - 1 - x; sx = y;        break;
    }
}

// w0: (6,1,7,7) -> F0T: [49][24] fp32
__global__ void lift_w0T_kernel(const float* __restrict__ w, float* __restrict__ f) {
    const int K = 7, KK = 49, OC = 24;
    int idx = blockIdx.x * blockDim.x + threadIdx.x;
    if (idx >= KK * OC) return;
    int oc = idx % OC; int kk = idx / OC;
    int y = kk / K, x = kk % K;
    int r = oc & 3, o = oc >> 2;
    int sy, sx; rot_src(r, K, y, x, sy, sx);
    f[idx] = w[o * KK + sy * K + sx];
}

// group-transform + split + pack into MFMA B-fragment order.
// elem idx = (((kpos*KC + kc)*NT + nc)*64 + lane)*8 + j
//   k = kc*32 + (lane>>4)*8 + j ; oc = nc*16 + (lane&15); hi at idx, lo at idx+total
__global__ void wfrag_kernel(const float* __restrict__ w, u16* __restrict__ wf,
                             int O, int I, int KC, int NT, int total) {
    int idx = blockIdx.x * blockDim.x + threadIdx.x;
    if (idx >= total) return;
    int j = idx & 7;
    int lane = (idx >> 3) & 63;
    int rest = idx >> 9;
    int nc = rest % NT; rest /= NT;
    int kc = rest % KC; int kpos = rest / KC;
    int ky = kpos / 5, kx = kpos % 5;
    int kk = ((lane >> 4) << 3) + j;
    int ic = kc * 32 + kk;
    int oc = nc * 16 + (lane & 15);
    float val = 0.f;
    if (ic < I * 4) {
        int o = oc >> 2, r = oc & 3, i = ic >> 2, s = ic & 3;
        int g = (s - r + 4) & 3;
        int sy, sx; rot_src(r, 5, ky, kx, sy, sx);
        val = w[(((o * I + i) * 4 + g) * 25) + sy * 5 + sx];
    }
    u16 hb = f2bf(val);
    u16 lb = f2bf(val - bf2f(hb));
    wf[idx] = hb;
    wf[idx + total] = lb;
}

// x (64,1,96,96) -> xp (64, 98, 100) fp32 with 1-border (pre-zeroed)
__global__ void pad_x_kernel(const float* __restrict__ x, float* __restrict__ xp) {
    int idx = blockIdx.x * blockDim.x + threadIdx.x;
    if (idx >= 64 * 96 * 96) return;
    int c = idx % 96; int t = idx / 96;
    int r = t % 96; int n = t / 96;
    xp[((size_t)n * 98 + r + 1) * 100 + c + 1] = x[idx];
}

// zero halo (thickness 2) fully + channel-pad chunks [CR8, ICO/8) elsewhere,
// both hi and lo planes.
__global__ void prep_pad_kernel(u16* __restrict__ buf, long LO, int NHW,
                                int Hp, int Wp, int ICO, int CR8) {
    int idx = blockIdx.x * blockDim.x + threadIdx.x;
    if (idx >= NHW) return;
    int c = idx % Wp; int t = idx / Wp;
    int r = t % Hp; int n = t / Hp;
    bool halo = (r < 2) || (r >= Hp - 2) || (c < 2) || (c >= Wp - 2);
    int c0 = halo ? 0 : CR8, c1 = ICO >> 3;
    if (c0 >= c1) return;
    size_t base = (((size_t)n * Hp + r) * Wp + c) * ICO;
    s16x8 z = {0, 0, 0, 0, 0, 0, 0, 0};
    for (int cc = c0; cc < c1; ++cc) {
        *(s16x8*)(buf + base + cc * 8) = z;
        *(s16x8*)(buf + LO + base + cc * 8) = z;
    }
}

// conv0: fp32 direct (IC=1, K=7, pad=1). One thread: ALL 24 oc x 4 x.
// Writes full 64B NHWC lines (ch 0..23 data, 24..31 zero), hi and lo planes.
__global__ __launch_bounds__(256) void conv0_kernel(
        const float* __restrict__ xp, const float* __restrict__ f0t,
        const float* __restrict__ b0, u16* __restrict__ p1, long p1LO) {
    int idx = blockIdx.x * blockDim.x + threadIdx.x;
    if (idx >= 64 * 92 * 23) return;
    int xq = idx % 23; int t = idx / 23;
    int oy = t % 92; int n = t / 92;
    float acc[24][4];
#pragma unroll
    for (int a = 0; a < 24; ++a)
#pragma unroll
        for (int b = 0; b < 4; ++b) acc[a][b] = 0.f;

    const float* ip = xp + ((size_t)n * 98 + oy) * 100 + xq * 4;
#pragma unroll
    for (int ky = 0; ky < 7; ++ky) {
        const float* row = ip + (size_t)ky * 100;
        float xv[12];
#pragma unroll
        for (int v = 0; v < 3; ++v)
            *reinterpret_cast<float4*>(&xv[4 * v]) =
                *reinterpret_cast<const float4*>(row + 4 * v);
#pragma unroll
        for (int kx = 0; kx < 7; ++kx) {
            const float* wp = f0t + (ky * 7 + kx) * 24;
#pragma unroll
            for (int qd = 0; qd < 6; ++qd) {
                float4 wv = *reinterpret_cast<const float4*>(wp + qd * 4);
#pragma unroll
                for (int jx = 0; jx < 4; ++jx) {
                    acc[qd * 4 + 0][jx] = fmaf(wv.x, xv[kx + jx], acc[qd * 4 + 0][jx]);
                    acc[qd * 4 + 1][jx] = fmaf(wv.y, xv[kx + jx], acc[qd * 4 + 1][jx]);
                    acc[qd * 4 + 2][jx] = fmaf(wv.z, xv[kx + jx], acc[qd * 4 + 2][jx]);
                    acc[qd * 4 + 3][jx] = fmaf(wv.w, xv[kx + jx], acc[qd * 4 + 3][jx]);
                }
            }
        }
    }
    float bv[6];
#pragma unroll
    for (int qd = 0; qd < 6; ++qd) bv[qd] = b0[qd];

    size_t ob = (((size_t)n * 96 + oy + 2) * 96 + xq * 4 + 2) * 32;
#pragma unroll
    for (int jx = 0; jx < 4; ++jx) {
        s16x8 hv[4], lv[4];
#pragma unroll
        for (int cc = 0; cc < 3; ++cc)
#pragma unroll
            for (int e = 0; e < 8; ++e) {
                int ch = cc * 8 + e;
                float v = fmaxf(acc[ch][jx] + bv[ch >> 2], 0.f);
                u16 hb = f2bf(v);
                u16 lb = f2bf(v - bf2f(hb));
                hv[cc][e] = (short)hb; lv[cc][e] = (short)lb;
            }
        hv[3] = s16x8{0,0,0,0,0,0,0,0}; lv[3] = s16x8{0,0,0,0,0,0,0,0};
#pragma unroll
        for (int cc = 0; cc < 4; ++cc) {
            *(s16x8*)(p1 + ob + jx * 32 + cc * 8) = hv[cc];
            *(s16x8*)(p1 + p1LO + ob + jx * 32 + cc * 8) = lv[cc];
        }
    }
}

// ---------------------------------------------------------------------------
// MFMA conv. wave = MT x-tiles x NTW oc-tiles x CR rows. Block = SW row-groups
// x OG oc-groups of waves (NW = SW*OG, 256 threads for all configs).
// Channel-split: KC passes, each stages 32 ch (hi+lo = 8 chunks per x) into
// LDS [row][x][chunk^ (x&7)]; acc persists across passes.
// ---------------------------------------------------------------------------
template <int IC32, int NT, int NTW, int MT, int CR, int SW, bool POOL, int XOFF>
__global__ __launch_bounds__(SW*(NT/NTW)*64, 2) void conv_mfma_kernel(
        const u16* __restrict__ act, long actLO,
        const u16* __restrict__ wf, int wfLO,
        const float* __restrict__ bias,
        u16* __restrict__ outP, long outLO,
        float* __restrict__ outF,
        int Hp, int Wp, int OH, int OW, int PH, int POW,
        int NRG, int NXS, int HpO, int WpO, int IC32O) {
    constexpr int OG = NT / NTW;
    constexpr int NW = SW * OG;
    constexpr int KC = IC32 / 32;
    constexpr int WT = MT * 16 + 4 + XOFF;
    constexpr int R  = CR * SW + 4;
    constexpr int CHUNKS = R * WT * 8;        // 16B chunks per pass
    __shared__ u16 lds[CHUNKS * 8];

    // bijective XCD swizzle (grid always a multiple of 8)
    int q8 = gridDim.x >> 3;
    int wid = (blockIdx.x & 7) * q8 + (blockIdx.x >> 3);
    int xs = wid % NXS; int t = wid / NXS;
    int rgrp = t % NRG; int n = t / NRG;

    int BR = rgrp * (CR * SW);      // conv-row base of block
    int rbase = BR + XOFF;          // input row base
    int xbase = xs * (MT * 16);     // conv-x base (== input x base; XOFF inside xl)

    int tid = threadIdx.x;
    int wv = tid >> 6;
    int lane = tid & 63;
    int l15 = lane & 15, lg = lane >> 4;
    int og = wv % OG, rg = wv / OG;

    f32x4 accP[CR][MT][NTW], accQ[CR][MT][NTW];
#pragma unroll
    for (int cr = 0; cr < CR; ++cr)
#pragma unroll
        for (int m = 0; m < MT; ++m)
#pragma unroll
            for (int nc = 0; nc < NTW; ++nc) {
                accP[cr][m][nc] = f32x4{0.f, 0.f, 0.f, 0.f};
                accQ[cr][m][nc] = f32x4{0.f, 0.f, 0.f, 0.f};
            }

    const u16* wfl = wf + (size_t)lane * 8;
    const u16* actn = act + ((size_t)n * Hp) * Wp * IC32;

    for (int kcp = 0; kcp < KC; ++kcp) {
        if (kcp) __syncthreads();
        // stage channels 32*kcp..+31, both planes, chunk-swizzled
        for (int u = tid; u < CHUNKS; u += NW * 64) {
            int c = u & 7; int rest = u >> 3;
            int xl = rest % WT; int row = rest / WT;
            int cg = c ^ (xl & 7);
            int sp = cg >> 2, cc4 = cg & 3;
            int gx = xbase + xl, gr = rbase + row;
            s16x8 v = {0, 0, 0, 0, 0, 0, 0, 0};
            if (gx < Wp && gr < Hp)
                v = *(const s16x8*)(actn + (size_t)sp * actLO +
                      ((size_t)gr * Wp + gx) * IC32 + (kcp * 4 + cc4) * 8);
            *(s16x8*)&lds[(size_t)u * 8] = v;
        }
        __syncthreads();

        for (int ky = 0; ky < 5; ++ky) {
            for (int kx = 0; kx < 5; ++kx) {
                int kpos = ky * 5 + kx;
                bf16x8 bh[NTW], bl[NTW];
#pragma unroll
                for (int nc = 0; nc < NTW; ++nc) {
                    const u16* bp = wfl +
                        ((size_t)(kpos * KC + kcp) * NT + og * NTW + nc) * 512;
                    bh[nc] = *(const bf16x8*)bp;
                    bl[nc] = *(const bf16x8*)(bp + wfLO);
                }
#pragma unroll
                for (int m = 0; m < MT; ++m) {
                    int xl = m * 16 + XOFF + l15 + kx;
                    int sw = xl & 7;
                    bf16x8 ah[CR], al[CR];
#pragma unroll
                    for (int cr = 0; cr < CR; ++cr) {
                        int row = rg * CR + cr + ky;
                        int base = (row * WT + xl) * 8;
                        ah[cr] = *(const bf16x8*)&lds[(size_t)(base + (lg ^ sw)) * 8];
                        al[cr] = *(const bf16x8*)&lds[(size_t)(base + ((4 + lg) ^ sw)) * 8];
                    }
#pragma unroll
                    for (int nc = 0; nc < NTW; ++nc)
#pragma unroll
                        for (int cr = 0; cr < CR; ++cr) {
                            accP[cr][m][nc] = __builtin_amdgcn_mfma_f32_16x16x32_bf16(
                                ah[cr], bh[nc], accP[cr][m][nc], 0, 0, 0);
                            accQ[cr][m][nc] = __builtin_amdgcn_mfma_f32_16x16x32_bf16(
                                ah[cr], bl[nc], accQ[cr][m][nc], 0, 0, 0);
                            accQ[cr][m][nc] = __builtin_amdgcn_mfma_f32_16x16x32_bf16(
                                al[cr], bh[nc], accQ[cr][m][nc], 0, 0, 0);
                        }
                }
            }
        }
    }

    // epilogue: C layout col(lane&15)=oc, row((lane>>4)*4+j)=x
#pragma unroll
    for (int nc = 0; nc < NTW; ++nc) {
        int oc = (og * NTW + nc) * 16 + l15;
        float bv = bias[oc >> 2];
#pragma unroll
        for (int m = 0; m < MT; ++m) {
            int gx0 = xbase + m * 16;
            if constexpr (POOL) {
                int p = rgrp * SW + rg;
                if (p < PH) {
                    float c0[4], c1[4];
#pragma unroll
                    for (int j = 0; j < 4; ++j) {
                        c0[j] = accP[0][m][nc][j] + accQ[0][m][nc][j];
                        c1[j] = accP[1][m][nc][j] + accQ[1][m][nc][j];
                    }
#pragma unroll
                    for (int a2 = 0; a2 < 2; ++a2) {
                        int px = (gx0 + lg * 4 + 2 * a2) >> 1;
                        if (px < POW) {
                            float mx = fmaxf(fmaxf(c0[2 * a2], c0[2 * a2 + 1]),
                                             fmaxf(c1[2 * a2], c1[2 * a2 + 1]));
                            float v = fmaxf(mx + bv, 0.f);
                            u16 hb = f2bf(v);
                            u16 lb = f2bf(v - bf2f(hb));
                            size_t o = (((size_t)n * HpO + p + 2) * WpO + px + 2) * IC32O + oc;
                            outP[o] = hb; outP[o + outLO] = lb;
                        }
                    }
                }
            } else {
#pragma unroll
                for (int cr = 0; cr < CR; ++cr) {
                    int oy = BR + rg * CR + cr;
                    if (oy < OH) {
#pragma unroll
                        for (int j = 0; j < 4; ++j) {
                            int gx = gx0 + lg * 4 + j;
                            if (gx < OW) {
                                float v = fmaxf(accP[cr][m][nc][j] + accQ[cr][m][nc][j] + bv, 0.f);
                                if (outF) {
                                    outF[(((size_t)n * OH + oy) * OW + gx) * (NT * 16) + oc] = v;
                                } else {
                                    u16 hb = f2bf(v);
                                    u16 lb = f2bf(v - bf2f(hb));
                                    size_t o = (((size_t)n * HpO + oy + 2) * WpO + gx + 2) * IC32O + oc;
                                    outP[o] = hb; outP[o + outLO] = lb;
                                }
                            }
                        }
                    }
                }
            }
        }
    }
}

// mean over 21x21 spatial of NHWC fp32 [64][21][21][64] -> (64,64)
__global__ void mean_nhwc_kernel(const float* __restrict__ in, float* __restrict__ out) {
    __shared__ float sm[256];
    int n = blockIdx.x;
    int c = threadIdx.x & 63, q = threadIdx.x >> 6;
    float s = 0.f;
    for (int p = q; p < 441; p += 4) s += in[((size_t)n * 441 + p) * 64 + c];
    sm[threadIdx.x] = s;
    __syncthreads();
    if (q == 0) out[n * 64 + c] = (sm[c] + sm[c + 64] + sm[c + 128] + sm[c + 192]) * (1.0f / 441.0f);
}

// single block: fc1 (64x64, relu) then fc2 (10x64)
__global__ void fc_kernel(const float* __restrict__ mean, const float* __restrict__ fw1,
                          const float* __restrict__ fb1, const float* __restrict__ fw2,
                          const float* __restrict__ fb2, float* __restrict__ out) {
    __shared__ float m[4096];
    __shared__ float h1[4096];
    int tid = threadIdx.x;
    for (int i = tid; i < 4096; i += 256) m[i] = mean[i];
    __syncthreads();
    for (int i = tid; i < 4096; i += 256) {
        int n = i >> 6, j = i & 63;
        float s = fb1[j];
        for (int k = 0; k < 64; ++k) s = fmaf(m[n * 64 + k], fw1[j * 64 + k], s);
        h1[i] = fmaxf(s, 0.f);
    }
    __syncthreads();
    for (int i = tid; i < 640; i += 256) {
        int n = i / 10, j2 = i % 10;
        float s = fb2[j2];
        for (int j = 0; j < 64; ++j) s = fmaf(h1[n * 64 + j], fw2[j2 * 64 + j], s);
        out[i] = s;
    }
}

extern "C" void kernel_launch(void* const* d_in, const int* in_sizes, int n_in,
                              void* d_out, int out_size, void* d_ws, size_t ws_size,
                              hipStream_t stream) {
    const float* x   = (const float*)d_in[0];
    const float* w0  = (const float*)d_in[1];
    const float* b0  = (const float*)d_in[2];
    const float* w1  = (const float*)d_in[3];
    const float* b1  = (const float*)d_in[4];
    const float* w2  = (const float*)d_in[5];
    const float* b2  = (const float*)d_in[6];
    const float* w3  = (const float*)d_in[7];
    const float* b3  = (const float*)d_in[8];
    const float* w4  = (const float*)d_in[9];
    const float* b4  = (const float*)d_in[10];
    const float* w5  = (const float*)d_in[11];
    const float* b5  = (const float*)d_in[12];
    const float* fw1 = (const float*)d_in[13];
    const float* fb1 = (const float*)d_in[14];
    const float* fw2 = (const float*)d_in[15];
    const float* fb2 = (const float*)d_in[16];

    char* ws = (char*)d_ws;
    if (ws_size < 128827392ull) return;

    float* F0   = (float*)(ws + 0);
    u16*   WF1  = (u16*)(ws + 8192);
    u16*   WF2  = (u16*)(ws + 161792);
    u16*   WF3  = (u16*)(ws + 468992);
    u16*   WF4  = (u16*)(ws + 1083392);
    u16*   WF5  = (u16*)(ws + 2004992);
    float* MEANB= (float*)(ws + 2619392);
    float* XP   = (float*)(ws + 2635776);
    float* C5   = (float*)(ws + 5144576);
    u16*   A    = (u16*)(ws + 12369920);    // P1 / P3 / P5
    u16*   B    = (u16*)(ws + 87867392);    // P2 / P4
    const long P1LO = 18874368;   // 64*96*96*32
    const long P2LO = 10240000;   // 64*50*50*64
    const long P4LO = 4478976;    // 64*27*27*96

    // --- weight transforms ---
    hipLaunchKernelGGL(lift_w0T_kernel, dim3(5), dim3(256), 0, stream, w0, F0);
    hipLaunchKernelGGL(wfrag_kernel, dim3(150), dim3(256), 0, stream, w1, WF1, 12, 6, 1, 3, 38400);
    hipLaunchKernelGGL(wfrag_kernel, dim3(300), dim3(256), 0, stream, w2, WF2, 12, 12, 2, 3, 76800);
    hipLaunchKernelGGL(wfrag_kernel, dim3(600), dim3(256), 0, stream, w3, WF3, 24, 12, 2, 6, 153600);
    hipLaunchKernelGGL(wfrag_kernel, dim3(900), dim3(256), 0, stream, w4, WF4, 24, 24, 3, 6, 230400);
    hipLaunchKernelGGL(wfrag_kernel, dim3(600), dim3(256), 0, stream, w5, WF5, 16, 24, 3, 4, 153600);

    // --- input pad (fp32) ---
    hipMemsetAsync(XP, 0, 2508800, stream);
    hipLaunchKernelGGL(pad_x_kernel, dim3(2304), dim3(256), 0, stream, x, XP);

    // --- P1 halo prep + conv0 ---
    hipLaunchKernelGGL(prep_pad_kernel, dim3((64*96*96 + 255)/256), dim3(256), 0, stream,
                       A, P1LO, 64*96*96, 96, 96, 32, 4);
    hipLaunchKernelGGL(conv0_kernel, dim3((64*92*23 + 255)/256), dim3(256), 0, stream,
                       XP, F0, b0, A, P1LO);

    // --- P2 prep + conv1 (+pool): P1 -> P2 [50][50][64] ---
    // wave: MT=3 x 3oc x CR=2(pool); SW=4 prow-waves; grid 64*12*2
    hipLaunchKernelGGL(prep_pad_kernel, dim3((64*50*50 + 255)/256), dim3(256), 0, stream,
                       B, P2LO, 64*50*50, 50, 50, 64, 6);
    hipLaunchKernelGGL((conv_mfma_kernel<32, 3, 3, 3, 2, 4, true, 0>), dim3(1536), dim3(256), 0, stream,
                       A, P1LO, WF1, 38400, b1, B, P2LO, (float*)nullptr,
                       96, 96, 92, 92, 46, 46, 12, 2, 50, 50, 64);

    // --- P3 prep + conv2: P2 -> P3 [50][50][64] ---
    // wave: MT=3 x 3oc x CR=1; SW=4 rows; grid 64*12
    hipLaunchKernelGGL(prep_pad_kernel, dim3((64*50*50 + 255)/256), dim3(256), 0, stream,
                       A, P2LO, 64*50*50, 50, 50, 64, 6);
    hipLaunchKernelGGL((conv_mfma_kernel<64, 3, 3, 3, 1, 4, false, 0>), dim3(768), dim3(256), 0, stream,
                       B, P2LO, WF2, 76800, b2, A, P2LO, (float*)nullptr,
                       50, 50, 46, 46, 0, 0, 12, 1, 50, 50, 64);

    // --- P4 prep + conv3 (+pool): P3 -> P4 [27][27][96] ---
    // wave: MT=3 x NTW=3 x CR=2(pool); SW=2 prows x OG=2; grid 64*12
    hipLaunchKernelGGL(prep_pad_kernel, dim3((64*27*27 + 255)/256), dim3(256), 0, stream,
                       B, P4LO, 64*27*27, 27, 27, 96, 12);
    hipLaunchKernelGGL((conv_mfma_kernel<64, 6, 3, 3, 2, 2, true, 0>), dim3(768), dim3(256), 0, stream,
                       A, P2LO, WF3, 153600, b3, B, P4LO, (float*)nullptr,
                       50, 50, 46, 46, 23, 23, 12, 1, 27, 27, 96);

    // --- P5 prep + conv4: P4 -> P5 [27][27][96] ---
    // wave: MT=2 x NTW=3 x CR=2; SW=2 x OG=2; grid 64*6
    hipLaunchKernelGGL(prep_pad_kernel, dim3((64*27*27 + 255)/256), dim3(256), 0, stream,
                       A, P4LO, 64*27*27, 27, 27, 96, 12);
    hipLaunchKernelGGL((conv_mfma_kernel<96, 6, 3, 2, 2, 2, false, 0>), dim3(384), dim3(256), 0, stream,
                       B, P4LO, WF4, 230400, b4, A, P4LO, (float*)nullptr,
                       27, 27, 23, 23, 0, 0, 6, 1, 27, 27, 96);

    // --- conv5: P5 -> C5 fp32 NHWC compact [21][21][64] ---
    // wave: MT=2 x NTW=2 x CR=2; SW=2 x OG=2; XOFF=1; grid 64*6
    hipLaunchKernelGGL((conv_mfma_kernel<96, 4, 2, 2, 2, 2, false, 1>), dim3(384), dim3(256), 0, stream,
                       A, P4LO, WF5, 153600, b5, (u16*)A, 0, C5,
                       27, 27, 21, 21, 0, 0, 6, 1, 27, 27, 96);

    // --- mean + fc ---
    hipLaunchKernelGGL(mean_nhwc_kernel, dim3(64), dim3(256), 0, stream, C5, MEANB);
    hipLaunchKernelGGL(fc_kernel, dim3(1), dim3(256), 0, stream,
                       MEANB, fw1, fb1, fw2, fb2, (float*)d_out);
}